// Round 10
// baseline (294.451 us; speedup 1.0000x reference)
//
#include <hip/hip_runtime.h>
#include <hip/hip_fp16.h>

#define DD 160
#define HH 192
#define WW 160
#define VOL (DD * HH * WW)   // 4915200
#define NB 2
#define NC 2

// ---- tiling ----
#define TZ 8
#define TY 8
#define TX 16
#define NTZ (DD / TZ)            // 20
#define NTY (HH / TY)            // 24
#define NTX (WW / TX)            // 10
#define TPB (NTZ * NTY * NTX)    // 4800 tiles per batch
#define NBLK (NB * TPB)          // 9600 blocks
#define NXCD 8

// z,y halo tightened to [-3,+3): box depth 14 (was 15). Voxels whose +1 tap
// lands at offset >= +3 beyond the tile (P ~0.13% on one edge row) take the
// exact f32 global fallback. Unlike R7's bug, the box bounds AND the inbox
// tests shrink together, so no path reads unstaged LDS rows.
#define RZM 14
#define RYM 14
#define RXP 24                   // row stride in u32 slots (96 B, 16B-aligned)
#define ZSTR (RYM * RXP)         // 336
#define CSTR (RZM * ZSTR)        // 4704 u32 slots = 18,816 B
// 18.8 KB LDS -> 8 blocks/CU = 32 waves = 100% of CU wave slots.

#define NROWS (RZM * RYM)        // 196 rows; 7 static sweeps of 32

typedef float    v4f  __attribute__((ext_vector_type(4)));
typedef unsigned v4u  __attribute__((ext_vector_type(4)));
typedef float    v2fu __attribute__((ext_vector_type(2), aligned(4)));

// Full-general per-voxel fallback from global memory (volume clamps, border
// zeroing, x-rebase). Used for flow outliers (beyond halo) in both paths.
__device__ __forceinline__ void gather_global(
    const float* xb0, const float* xb1,
    float pz, float py, float px, float& s0, float& s1)
{
    float z0f = floorf(pz), y0f = floorf(py), x0f = floorf(px);
    float fz = pz - z0f, fy = py - y0f, fx = px - x0f;
    int z0 = (int)z0f, y0 = (int)y0f, x0 = (int)x0f;
    int z1 = z0 + 1,  y1 = y0 + 1,  x1 = x0 + 1;

    float wz0 = (z0 >= 0 && z0 < DD) ? (1.0f - fz) : 0.0f;
    float wz1 = (z1 >= 0 && z1 < DD) ? fz : 0.0f;
    float wy0 = (y0 >= 0 && y0 < HH) ? (1.0f - fy) : 0.0f;
    float wy1 = (y1 >= 0 && y1 < HH) ? fy : 0.0f;
    float wx0 = (x0 >= 0 && x0 < WW) ? (1.0f - fx) : 0.0f;
    float wx1 = (x1 >= 0 && x1 < WW) ? fx : 0.0f;

    int z0c = min(max(z0, 0), DD - 1);
    int z1c = min(max(z1, 0), DD - 1);
    int y0c = min(max(y0, 0), HH - 1);
    int y1c = min(max(y1, 0), HH - 1);
    int x0c = min(max(x0, 0), WW - 1);

    int base = min(x0c, WW - 2);
    float a  = ((x0c == base) ? wx0 : 0.0f)
             + ((min(max(x1, 0), WW - 1) == base) ? wx1 : 0.0f);
    float bb = (wx0 + wx1) - a;

    float w0 = wz0 * wy0, w1 = wz0 * wy1, w2 = wz1 * wy0, w3 = wz1 * wy1;
    int p00 = (z0c * HH + y0c) * WW + base;
    int p01 = (z0c * HH + y1c) * WW + base;
    int p10 = (z1c * HH + y0c) * WW + base;
    int p11 = (z1c * HH + y1c) * WW + base;

    v2fu c;
    s0 = 0.0f; s1 = 0.0f;
    c = *(const v2fu*)(xb0 + p00); s0 += (w0 * a) * c.x + (w0 * bb) * c.y;
    c = *(const v2fu*)(xb0 + p01); s0 += (w1 * a) * c.x + (w1 * bb) * c.y;
    c = *(const v2fu*)(xb0 + p10); s0 += (w2 * a) * c.x + (w2 * bb) * c.y;
    c = *(const v2fu*)(xb0 + p11); s0 += (w3 * a) * c.x + (w3 * bb) * c.y;
    c = *(const v2fu*)(xb1 + p00); s1 += (w0 * a) * c.x + (w0 * bb) * c.y;
    c = *(const v2fu*)(xb1 + p01); s1 += (w1 * a) * c.x + (w1 * bb) * c.y;
    c = *(const v2fu*)(xb1 + p10); s1 += (w2 * a) * c.x + (w2 * bb) * c.y;
    c = *(const v2fu*)(xb1 + p11); s1 += (w3 * a) * c.x + (w3 * bb) * c.y;
}

// R9 post-mortem: removing VALU work left time unchanged (VALUBusy 37->31%,
// dur flat) -> stall-dominated overlap-limited regime; the lever is wave
// count. This round: box depth 15->14 (halo [-3,+3) in z,y) => 18.8 KB LDS
// => 8 blocks/CU = 32 waves (100% slots); staging rows 225->196 (-13%).
__global__ __launch_bounds__(256, 8) void warp_kernel(
    const float* __restrict__ x,
    const float* __restrict__ flow,
    float* __restrict__ out)
{
    __shared__ unsigned lds[CSTR];

    // XCD-contiguous swizzle (9600 = 8 * 1200).
    int bid = blockIdx.x;
    int vid = (bid & (NXCD - 1)) * (NBLK / NXCD) + (bid >> 3);

    int b  = vid / TPB;
    int r  = vid - b * TPB;
    int tz = r / (NTY * NTX);
    int r2 = r - tz * (NTY * NTX);
    int ty = r2 / NTX;
    int tx = r2 - ty * NTX;

    int oz = tz * TZ, oy = ty * TY, ox = tx * TX;

    // staged box: z,y cover flow in [-3,+3) incl. +1 tap (depth <= 14);
    // x covers [-3,+4) incl. +1 tap (span <= 24, 4-aligned base).
    int bz0 = max(oz - 3, 0), bz1 = min(oz + TZ + 3, DD);
    int by0 = max(oy - 3, 0), by1 = min(oy + TY + 3, HH);
    int bx0 = max(ox - 3, 0) & ~3;
    int bx1 = min(ox + TX + 4, WW);

    // interior <=> staged box untouched by volume clamping
    bool interior = (oz >= 3) && (oz + TZ + 3 <= DD) &&
                    (oy >= 3) && (oy + TY + 3 <= HH) &&
                    (ox >= 4) && (ox + TX + 4 <= WW);

    int tid = threadIdx.x;

    const float* fb  = flow + (size_t)b * 3 * VOL;
    const float* xb0 = x + (size_t)b * NC * VOL;
    const float* xb1 = xb0 + VOL;
    float* ob        = out + (size_t)b * NC * VOL;

    // ---- flow prefetch (issue-early) ----
    float pfz[4], pfy[4], pfx[4];
    int   gidx[4];
#pragma unroll
    for (int i = 0; i < 4; ++i) {
        int V  = tid + 256 * i;
        int xl = V & 15, yl = (V >> 4) & 7, zl = V >> 7;
        int gi = ((oz + zl) * HH + (oy + yl)) * WW + (ox + xl);
        gidx[i] = gi;
        pfz[i] = __builtin_nontemporal_load(fb + gi);
        pfy[i] = __builtin_nontemporal_load(fb + gi + VOL);
        pfx[i] = __builtin_nontemporal_load(fb + gi + 2 * VOL);
    }

    // ---- stage both channels, fp16-packed (STATIC 7 sweeps) ----
    // Rows whose clamped global coords fall outside the box load garbage from
    // a clamped in-buffer address into LDS slots the inbox path never reads.
    {
        int lane8 = tid & 7, rowid = tid >> 3;
        const size_t LIM = (size_t)NB * NC * VOL - 4;
        if (lane8 < 6) {
#pragma unroll
            for (int k = 0; k < 7; ++k) {
                int rr = rowid + 32 * k;
                if (rr < NROWS) {             // folds away for k < 6
                    int z = rr / RYM;         // compile-time divisor (14)
                    int y = rr - z * RYM;
                    size_t g0 = (size_t)b * NC * VOL
                              + (size_t)((bz0 + z) * HH + (by0 + y)) * WW
                              + (size_t)(bx0 + lane8 * 4);
                    size_t g1 = g0 + VOL;
                    if (g0 > LIM) g0 = LIM;
                    if (g1 > LIM) g1 = LIM;
                    v4f a0 = *(const v4f*)(x + g0);
                    v4f a1 = *(const v4f*)(x + g1);
                    v4u pk;
#pragma unroll
                    for (int q = 0; q < 4; ++q) {
                        __half2 h = __halves2half2(__float2half(a0[q]),
                                                   __float2half(a1[q]));
                        pk[q] = __builtin_bit_cast(unsigned, h);
                    }
                    *(v4u*)(lds + z * ZSTR + y * RXP + lane8 * 4) = pk;
                }
            }
        }
    }
    __syncthreads();

    if (interior) {
        // ================= interior fast path =================
#pragma unroll
        for (int i = 0; i < 4; ++i) {
            int V  = tid + 256 * i;
            int xl = V & 15, yl = (V >> 4) & 7, zl = V >> 7;
            int gz = oz + zl, gy = oy + yl, gx = ox + xl;
            int gi = gidx[i];

            float pz = gz + pfz[i], py = gy + pfy[i], px = gx + pfx[i];

            float z0f = floorf(pz), y0f = floorf(py), x0f = floorf(px);
            float fz = pz - z0f, fy = py - y0f, fx = px - x0f;
            int z0 = (int)z0f, y0 = (int)y0f, x0 = (int)x0f;

            bool ok = (z0 >= bz0) && (z0 <= bz1 - 2) &&
                      (y0 >= by0) && (y0 <= by1 - 2) &&
                      (x0 >= bx0) && (x0 <= bx1 - 2);

            float s0, s1;
            if (ok) {
                float wz0 = 1.0f - fz, wy0 = 1.0f - fy;
                float wx0 = 1.0f - fx, wx1 = fx;
                float w0 = wz0 * wy0, w1 = wz0 * fy;
                float w2 = fz  * wy0, w3 = fz  * fy;

                int A00 = (z0 - bz0) * ZSTR + (y0 - by0) * RXP + (x0 - bx0);
                int A01 = A00 + RXP;
                int A10 = A00 + ZSTR;
                int A11 = A10 + RXP;

                s0 = 0.0f; s1 = 0.0f;
#pragma unroll
                for (int k = 0; k < 4; ++k) {
                    int   A = (k == 0) ? A00 : (k == 1) ? A01
                            : (k == 2) ? A10 : A11;
                    float w = (k == 0) ? w0  : (k == 1) ? w1
                            : (k == 2) ? w2  : w3;
                    float wa = w * wx0, wb = w * wx1;
                    unsigned m0 = lds[A];          // {c0[x],   c1[x]}
                    unsigned m1 = lds[A + 1];      // {c0[x+1], c1[x+1]}
                    float2 f0 = __half22float2(__builtin_bit_cast(__half2, m0));
                    float2 f1 = __half22float2(__builtin_bit_cast(__half2, m1));
                    s0 += wa * f0.x + wb * f1.x;
                    s1 += wa * f0.y + wb * f1.y;
                }
            } else {
                gather_global(xb0, xb1, pz, py, px, s0, s1);
            }

            __builtin_nontemporal_store(s0, ob + gi);
            __builtin_nontemporal_store(s1, ob + gi + VOL);
        }
    } else {
        // ================= boundary path =================
#pragma unroll
        for (int i = 0; i < 4; ++i) {
            int V  = tid + 256 * i;
            int xl = V & 15, yl = (V >> 4) & 7, zl = V >> 7;
            int gz = oz + zl, gy = oy + yl, gx = ox + xl;
            int gi = gidx[i];

            float pz = gz + pfz[i], py = gy + pfy[i], px = gx + pfx[i];

            float z0f = floorf(pz), y0f = floorf(py), x0f = floorf(px);
            float fz = pz - z0f, fy = py - y0f, fx = px - x0f;
            int z0 = (int)z0f, y0 = (int)y0f, x0 = (int)x0f;
            int z1 = z0 + 1,  y1 = y0 + 1,  x1 = x0 + 1;

            float wz0 = (z0 >= 0 && z0 < DD) ? (1.0f - fz) : 0.0f;
            float wz1 = (z1 >= 0 && z1 < DD) ? fz : 0.0f;
            float wy0 = (y0 >= 0 && y0 < HH) ? (1.0f - fy) : 0.0f;
            float wy1 = (y1 >= 0 && y1 < HH) ? fy : 0.0f;
            float wx0 = (x0 >= 0 && x0 < WW) ? (1.0f - fx) : 0.0f;
            float wx1 = (x1 >= 0 && x1 < WW) ? fx : 0.0f;

            int z0c = min(max(z0, 0), DD - 1);
            int z1c = min(max(z1, 0), DD - 1);
            int y0c = min(max(y0, 0), HH - 1);
            int y1c = min(max(y1, 0), HH - 1);
            int x0c = min(max(x0, 0), WW - 1);
            int x1c = min(max(x1, 0), WW - 1);

            int base = min(x0c, WW - 2);

            float a  = ((x0c == base) ? wx0 : 0.0f)
                     + ((x1c == base) ? wx1 : 0.0f);
            float bb = (wx0 + wx1) - a;

            float w0 = wz0 * wy0, w1 = wz0 * wy1;
            float w2 = wz1 * wy0, w3 = wz1 * wy1;
            float wA0 = w0 * a,  wB0 = w0 * bb;
            float wA1 = w1 * a,  wB1 = w1 * bb;
            float wA2 = w2 * a,  wB2 = w2 * bb;
            float wA3 = w3 * a,  wB3 = w3 * bb;

            bool inbox = (z0c >= bz0) && (z1c < bz1) &&
                         (y0c >= by0) && (y1c < by1) &&
                         (base >= bx0) && (base + 1 < bx1);

            float s0, s1;
            if (inbox) {
                int lx  = base - bx0;
                int A00 = (z0c - bz0) * ZSTR + (y0c - by0) * RXP + lx;
                int A01 = (z0c - bz0) * ZSTR + (y1c - by0) * RXP + lx;
                int A10 = (z1c - bz0) * ZSTR + (y0c - by0) * RXP + lx;
                int A11 = (z1c - bz0) * ZSTR + (y1c - by0) * RXP + lx;
                s0 = 0.0f; s1 = 0.0f;
#pragma unroll
                for (int k = 0; k < 4; ++k) {
                    int   A  = (k == 0) ? A00 : (k == 1) ? A01
                             : (k == 2) ? A10 : A11;
                    float wa = (k == 0) ? wA0 : (k == 1) ? wA1
                             : (k == 2) ? wA2 : wA3;
                    float wb = (k == 0) ? wB0 : (k == 1) ? wB1
                             : (k == 2) ? wB2 : wB3;
                    unsigned m0 = lds[A];
                    unsigned m1 = lds[A + 1];
                    float2 f0 = __half22float2(__builtin_bit_cast(__half2, m0));
                    float2 f1 = __half22float2(__builtin_bit_cast(__half2, m1));
                    s0 += wa * f0.x + wb * f1.x;
                    s1 += wa * f0.y + wb * f1.y;
                }
            } else {
                gather_global(xb0, xb1, pz, py, px, s0, s1);
            }

            __builtin_nontemporal_store(s0, ob + gi);
            __builtin_nontemporal_store(s1, ob + gi + VOL);
        }
    }
}

extern "C" void kernel_launch(void* const* d_in, const int* in_sizes, int n_in,
                              void* d_out, int out_size, void* d_ws, size_t ws_size,
                              hipStream_t stream) {
    const float* x    = (const float*)d_in[0];
    const float* flow = (const float*)d_in[1];
    float* out        = (float*)d_out;

    warp_kernel<<<NBLK, 256, 0, stream>>>(x, flow, out);
}

// Round 12
// 281.346 us; speedup vs baseline: 1.0466x; 1.0466x over previous
//
#include <hip/hip_runtime.h>
#include <hip/hip_fp16.h>

#define DD 160
#define HH 192
#define WW 160
#define VOL (DD * HH * WW)   // 4915200
#define NB 2
#define NC 2

// ---- tiling: z-PAIRED tiles (16x8x16 output per block) ----
#define TZ 16
#define TY 8
#define TX 16
#define NTZ (DD / TZ)            // 10
#define NTY (HH / TY)            // 24
#define NTX (WW / TX)            // 10
#define TPB (NTZ * NTY * NTX)    // 2400 tiles per batch
#define NBLK (NB * TPB)          // 4800 blocks
#define NXCD 8

// halo [-3,+4) incl. the +1 tap on all axes (R8-proven; R10's tighter halo
// doubled fallback rate and regressed). Box: (16+7) x (8+7) x 24 slots.
// One staged box now serves 2048 output voxels: 4.04 staged slots/voxel vs
// R8's 5.27 (-23% staging traffic+instructions, half the barriers/voxel).
#define RZM 23
#define RYM 15
#define RXP 24                   // row stride in u32 slots (96 B)
#define ZSTR (RYM * RXP)         // 360
#define CSTR (RZM * ZSTR)        // 8280 u32 slots = 33,120 B
// 33.1 KB LDS -> 4 blocks/CU (16 waves). R10 evidence: occupancy 60->76% had
// zero effect on time, so trading waves for stage amortization is the bet.

#define NROWS (RZM * RYM)        // 345 rows; 11 static sweeps of 32

typedef float    v4f  __attribute__((ext_vector_type(4)));
typedef unsigned v4u  __attribute__((ext_vector_type(4)));
typedef float    v2fu __attribute__((ext_vector_type(2), aligned(4)));
typedef __fp16   hf2  __attribute__((ext_vector_type(2)));   // cvt_pkrtz ret type

// Full-general per-voxel fallback from global memory (volume clamps, border
// zeroing, x-rebase). Used for flow outliers (beyond halo) in both paths.
__device__ __forceinline__ void gather_global(
    const float* xb0, const float* xb1,
    float pz, float py, float px, float& s0, float& s1)
{
    float z0f = floorf(pz), y0f = floorf(py), x0f = floorf(px);
    float fz = pz - z0f, fy = py - y0f, fx = px - x0f;
    int z0 = (int)z0f, y0 = (int)y0f, x0 = (int)x0f;
    int z1 = z0 + 1,  y1 = y0 + 1,  x1 = x0 + 1;

    float wz0 = (z0 >= 0 && z0 < DD) ? (1.0f - fz) : 0.0f;
    float wz1 = (z1 >= 0 && z1 < DD) ? fz : 0.0f;
    float wy0 = (y0 >= 0 && y0 < HH) ? (1.0f - fy) : 0.0f;
    float wy1 = (y1 >= 0 && y1 < HH) ? fy : 0.0f;
    float wx0 = (x0 >= 0 && x0 < WW) ? (1.0f - fx) : 0.0f;
    float wx1 = (x1 >= 0 && x1 < WW) ? fx : 0.0f;

    int z0c = min(max(z0, 0), DD - 1);
    int z1c = min(max(z1, 0), DD - 1);
    int y0c = min(max(y0, 0), HH - 1);
    int y1c = min(max(y1, 0), HH - 1);
    int x0c = min(max(x0, 0), WW - 1);

    int base = min(x0c, WW - 2);
    float a  = ((x0c == base) ? wx0 : 0.0f)
             + ((min(max(x1, 0), WW - 1) == base) ? wx1 : 0.0f);
    float bb = (wx0 + wx1) - a;

    float w0 = wz0 * wy0, w1 = wz0 * wy1, w2 = wz1 * wy0, w3 = wz1 * wy1;
    int p00 = (z0c * HH + y0c) * WW + base;
    int p01 = (z0c * HH + y1c) * WW + base;
    int p10 = (z1c * HH + y0c) * WW + base;
    int p11 = (z1c * HH + y1c) * WW + base;

    v2fu c;
    s0 = 0.0f; s1 = 0.0f;
    c = *(const v2fu*)(xb0 + p00); s0 += (w0 * a) * c.x + (w0 * bb) * c.y;
    c = *(const v2fu*)(xb0 + p01); s0 += (w1 * a) * c.x + (w1 * bb) * c.y;
    c = *(const v2fu*)(xb0 + p10); s0 += (w2 * a) * c.x + (w2 * bb) * c.y;
    c = *(const v2fu*)(xb0 + p11); s0 += (w3 * a) * c.x + (w3 * bb) * c.y;
    c = *(const v2fu*)(xb1 + p00); s1 += (w0 * a) * c.x + (w0 * bb) * c.y;
    c = *(const v2fu*)(xb1 + p01); s1 += (w1 * a) * c.x + (w1 * bb) * c.y;
    c = *(const v2fu*)(xb1 + p10); s1 += (w2 * a) * c.x + (w2 * bb) * c.y;
    c = *(const v2fu*)(xb1 + p11); s1 += (w3 * a) * c.x + (w3 * bb) * c.y;
}

// R10 post-mortem: occupancy 60->76% with NO time gain, VALU removal with no
// gain -> neither waves nor instructions are binding; the residual is per-
// block phase cost (stage round-trip + barrier + drain) and per-tile halo
// re-staging. This round: z-paired tiles amortize one staged box over 2x the
// output (staging slots/voxel 5.27->4.04), halo restored to R8's [-3,+4),
// cvt_pkrtz packs both channels in one VALU op.
__global__ __launch_bounds__(256, 4) void warp_kernel(
    const float* __restrict__ x,
    const float* __restrict__ flow,
    float* __restrict__ out)
{
    __shared__ unsigned lds[CSTR];

    // XCD-contiguous swizzle (4800 = 8 * 600).
    int bid = blockIdx.x;
    int vid = (bid & (NXCD - 1)) * (NBLK / NXCD) + (bid >> 3);

    int b  = vid / TPB;
    int r  = vid - b * TPB;
    int tz = r / (NTY * NTX);
    int r2 = r - tz * (NTY * NTX);
    int ty = r2 / NTX;
    int tx = r2 - ty * NTX;

    int oz = tz * TZ, oy = ty * TY, ox = tx * TX;

    // staged box covers flow in [-3,+4) incl. the +1 tap on all axes
    int bz0 = max(oz - 3, 0), bz1 = min(oz + TZ + 4, DD);
    int by0 = max(oy - 3, 0), by1 = min(oy + TY + 4, HH);
    int bx0 = max(ox - 3, 0) & ~3;
    int bx1 = min(ox + TX + 4, WW);

    // interior <=> staged box untouched by volume clamping
    bool interior = (oz >= 3) && (oz + TZ + 4 <= DD) &&
                    (oy >= 3) && (oy + TY + 4 <= HH) &&
                    (ox >= 4) && (ox + TX + 4 <= WW);

    int tid = threadIdx.x;

    const float* fb  = flow + (size_t)b * 3 * VOL;
    const float* xb0 = x + (size_t)b * NC * VOL;
    const float* xb1 = xb0 + VOL;
    float* ob        = out + (size_t)b * NC * VOL;

    // ---- flow prefetch (issue-early): 24 loads in flight over staging ----
    float pfz[8], pfy[8], pfx[8];
    int   gidx[8];
#pragma unroll
    for (int i = 0; i < 8; ++i) {
        int V  = tid + 256 * i;
        int xl = V & 15, yl = (V >> 4) & 7, zl = V >> 7;   // zl in 0..15
        int gi = ((oz + zl) * HH + (oy + yl)) * WW + (ox + xl);
        gidx[i] = gi;
        pfz[i] = __builtin_nontemporal_load(fb + gi);
        pfy[i] = __builtin_nontemporal_load(fb + gi + VOL);
        pfx[i] = __builtin_nontemporal_load(fb + gi + 2 * VOL);
    }

    // ---- stage both channels, fp16-packed (STATIC 11 sweeps) ----
    // Rows whose clamped global coords fall outside the box load garbage from
    // a clamped in-buffer address into LDS slots the inbox path never reads.
    {
        int lane8 = tid & 7, rowid = tid >> 3;
        const size_t LIM = (size_t)NB * NC * VOL - 4;
        if (lane8 < 6) {
#pragma unroll
            for (int k = 0; k < 11; ++k) {
                int rr = rowid + 32 * k;
                if (rr < NROWS) {             // folds away for k < 10
                    int z = rr / RYM;         // compile-time divisor (15)
                    int y = rr - z * RYM;
                    size_t g0 = (size_t)b * NC * VOL
                              + (size_t)((bz0 + z) * HH + (by0 + y)) * WW
                              + (size_t)(bx0 + lane8 * 4);
                    size_t g1 = g0 + VOL;
                    if (g0 > LIM) g0 = LIM;
                    if (g1 > LIM) g1 = LIM;
                    v4f a0 = *(const v4f*)(x + g0);
                    v4f a1 = *(const v4f*)(x + g1);
                    v4u pk;
#pragma unroll
                    for (int q = 0; q < 4; ++q) {
                        // one VALU op packs {f16(c0) lo, f16(c1) hi}
                        hf2 h = __builtin_amdgcn_cvt_pkrtz(a0[q], a1[q]);
                        pk[q] = __builtin_bit_cast(unsigned, h);
                    }
                    *(v4u*)(lds + z * ZSTR + y * RXP + lane8 * 4) = pk;
                }
            }
        }
    }
    __syncthreads();

    if (interior) {
        // ================= interior fast path =================
#pragma unroll
        for (int i = 0; i < 8; ++i) {
            int V  = tid + 256 * i;
            int xl = V & 15, yl = (V >> 4) & 7, zl = V >> 7;
            int gz = oz + zl, gy = oy + yl, gx = ox + xl;
            int gi = gidx[i];

            float pz = gz + pfz[i], py = gy + pfy[i], px = gx + pfx[i];

            float z0f = floorf(pz), y0f = floorf(py), x0f = floorf(px);
            float fz = pz - z0f, fy = py - y0f, fx = px - x0f;
            int z0 = (int)z0f, y0 = (int)y0f, x0 = (int)x0f;

            bool ok = (z0 >= bz0) && (z0 <= bz1 - 2) &&
                      (y0 >= by0) && (y0 <= by1 - 2) &&
                      (x0 >= bx0) && (x0 <= bx1 - 2);

            float s0, s1;
            if (ok) {
                float wz0 = 1.0f - fz, wy0 = 1.0f - fy;
                float wx0 = 1.0f - fx, wx1 = fx;
                float w0 = wz0 * wy0, w1 = wz0 * fy;
                float w2 = fz  * wy0, w3 = fz  * fy;

                int A00 = (z0 - bz0) * ZSTR + (y0 - by0) * RXP + (x0 - bx0);
                int A01 = A00 + RXP;
                int A10 = A00 + ZSTR;
                int A11 = A10 + RXP;

                s0 = 0.0f; s1 = 0.0f;
#pragma unroll
                for (int k = 0; k < 4; ++k) {
                    int   A = (k == 0) ? A00 : (k == 1) ? A01
                            : (k == 2) ? A10 : A11;
                    float w = (k == 0) ? w0  : (k == 1) ? w1
                            : (k == 2) ? w2  : w3;
                    float wa = w * wx0, wb = w * wx1;
                    unsigned m0 = lds[A];          // {c0[x],   c1[x]}
                    unsigned m1 = lds[A + 1];      // {c0[x+1], c1[x+1]}
                    float2 f0 = __half22float2(__builtin_bit_cast(__half2, m0));
                    float2 f1 = __half22float2(__builtin_bit_cast(__half2, m1));
                    s0 += wa * f0.x + wb * f1.x;
                    s1 += wa * f0.y + wb * f1.y;
                }
            } else {
                gather_global(xb0, xb1, pz, py, px, s0, s1);
            }

            __builtin_nontemporal_store(s0, ob + gi);
            __builtin_nontemporal_store(s1, ob + gi + VOL);
        }
    } else {
        // ================= boundary path =================
#pragma unroll
        for (int i = 0; i < 8; ++i) {
            int V  = tid + 256 * i;
            int xl = V & 15, yl = (V >> 4) & 7, zl = V >> 7;
            int gz = oz + zl, gy = oy + yl, gx = ox + xl;
            int gi = gidx[i];

            float pz = gz + pfz[i], py = gy + pfy[i], px = gx + pfx[i];

            float z0f = floorf(pz), y0f = floorf(py), x0f = floorf(px);
            float fz = pz - z0f, fy = py - y0f, fx = px - x0f;
            int z0 = (int)z0f, y0 = (int)y0f, x0 = (int)x0f;
            int z1 = z0 + 1,  y1 = y0 + 1,  x1 = x0 + 1;

            float wz0 = (z0 >= 0 && z0 < DD) ? (1.0f - fz) : 0.0f;
            float wz1 = (z1 >= 0 && z1 < DD) ? fz : 0.0f;
            float wy0 = (y0 >= 0 && y0 < HH) ? (1.0f - fy) : 0.0f;
            float wy1 = (y1 >= 0 && y1 < HH) ? fy : 0.0f;
            float wx0 = (x0 >= 0 && x0 < WW) ? (1.0f - fx) : 0.0f;
            float wx1 = (x1 >= 0 && x1 < WW) ? fx : 0.0f;

            int z0c = min(max(z0, 0), DD - 1);
            int z1c = min(max(z1, 0), DD - 1);
            int y0c = min(max(y0, 0), HH - 1);
            int y1c = min(max(y1, 0), HH - 1);
            int x0c = min(max(x0, 0), WW - 1);
            int x1c = min(max(x1, 0), WW - 1);

            int base = min(x0c, WW - 2);

            float a  = ((x0c == base) ? wx0 : 0.0f)
                     + ((x1c == base) ? wx1 : 0.0f);
            float bb = (wx0 + wx1) - a;

            float w0 = wz0 * wy0, w1 = wz0 * wy1;
            float w2 = wz1 * wy0, w3 = wz1 * wy1;
            float wA0 = w0 * a,  wB0 = w0 * bb;
            float wA1 = w1 * a,  wB1 = w1 * bb;
            float wA2 = w2 * a,  wB2 = w2 * bb;
            float wA3 = w3 * a,  wB3 = w3 * bb;

            bool inbox = (z0c >= bz0) && (z1c < bz1) &&
                         (y0c >= by0) && (y1c < by1) &&
                         (base >= bx0) && (base + 1 < bx1);

            float s0, s1;
            if (inbox) {
                int lx  = base - bx0;
                int A00 = (z0c - bz0) * ZSTR + (y0c - by0) * RXP + lx;
                int A01 = (z0c - bz0) * ZSTR + (y1c - by0) * RXP + lx;
                int A10 = (z1c - bz0) * ZSTR + (y0c - by0) * RXP + lx;
                int A11 = (z1c - bz0) * ZSTR + (y1c - by0) * RXP + lx;
                s0 = 0.0f; s1 = 0.0f;
#pragma unroll
                for (int k = 0; k < 4; ++k) {
                    int   A  = (k == 0) ? A00 : (k == 1) ? A01
                             : (k == 2) ? A10 : A11;
                    float wa = (k == 0) ? wA0 : (k == 1) ? wA1
                             : (k == 2) ? wA2 : wA3;
                    float wb = (k == 0) ? wB0 : (k == 1) ? wB1
                             : (k == 2) ? wB2 : wB3;
                    unsigned m0 = lds[A];
                    unsigned m1 = lds[A + 1];
                    float2 f0 = __half22float2(__builtin_bit_cast(__half2, m0));
                    float2 f1 = __half22float2(__builtin_bit_cast(__half2, m1));
                    s0 += wa * f0.x + wb * f1.x;
                    s1 += wa * f0.y + wb * f1.y;
                }
            } else {
                gather_global(xb0, xb1, pz, py, px, s0, s1);
            }

            __builtin_nontemporal_store(s0, ob + gi);
            __builtin_nontemporal_store(s1, ob + gi + VOL);
        }
    }
}

extern "C" void kernel_launch(void* const* d_in, const int* in_sizes, int n_in,
                              void* d_out, int out_size, void* d_ws, size_t ws_size,
                              hipStream_t stream) {
    const float* x    = (const float*)d_in[0];
    const float* flow = (const float*)d_in[1];
    float* out        = (float*)d_out;

    warp_kernel<<<NBLK, 256, 0, stream>>>(x, flow, out);
}